// Round 9
// baseline (494.052 us; speedup 1.0000x reference)
//
#include <hip/hip_runtime.h>
#include <hip/hip_bf16.h>

using bf16 = __hip_bfloat16;
using bf16x8 = __attribute__((ext_vector_type(8))) __bf16;
using f32x4  = __attribute__((ext_vector_type(4))) float;
using u32x4  = __attribute__((ext_vector_type(4))) unsigned;
typedef unsigned short ushort_t;

#define BM 128
#define BN 128
#define BK 32

// B=4, L=512, D=768, W=12, K_spans=6144, rows_out = B*K = 24576

__device__ __forceinline__ void gl_lds16(const void* g, void* l) {
  __builtin_amdgcn_global_load_lds(
      (const __attribute__((address_space(1))) void*)g,
      (__attribute__((address_space(3))) void*)l, 16, 0, 0);
}

__device__ __forceinline__ ushort_t f2bf(float f) {  // RNE fp32->bf16
  unsigned u = __float_as_uint(f);
  u += 0x7FFF + ((u >> 16) & 1);
  return (ushort_t)(u >> 16);
}

// flags[0]=1 if float inputs are stored as bf16 (else fp32)
// flags[1]=1 if span_idx is int64 (else int32)
__global__ void sniff(const unsigned* __restrict__ w1,
                      const unsigned* __restrict__ idx, int* flags) {
  __shared__ int cnt[2];
  if (threadIdx.x == 0) { cnt[0] = 0; cnt[1] = 0; }
  __syncthreads();
  int t = threadIdx.x;  // 256 threads
  int c0 = 0;
  for (int k = 0; k < 4; ++k) {
    unsigned lo = w1[t * 4 + k] & 0xFFFFu;
    unsigned e = (lo >> 7) & 0xFF;
    if (e <= 122) c0++;
  }
  int c1 = (idx[2 * t + 1] != 0) ? 1 : 0;
  atomicAdd(&cnt[0], c0);
  atomicAdd(&cnt[1], c1);
  __syncthreads();
  if (threadIdx.x == 0) {
    flags[0] = (cnt[0] >= 900) ? 1 : 0;
    flags[1] = (cnt[1] == 0) ? 1 : 0;
  }
}

__global__ void norm_idx(const int* __restrict__ flags, const void* __restrict__ src,
                         int* __restrict__ dst) {
  int i = blockIdx.x * 256 + threadIdx.x;  // grid covers exactly 49152
  int v = flags[1] ? (int)((const long long*)src)[i] : ((const int*)src)[i];
  dst[i] = v;
}

// One kernel converts h + all 6 weights into the contiguous bf16 region at dst.
__global__ void cvt_all(const int* __restrict__ flags,
                        const void* s0, const void* s1, const void* s2,
                        const void* s3, const void* s4, const void* s5,
                        const void* s6, ushort_t* __restrict__ dst) {
  long i = ((long)blockIdx.x * 256 + threadIdx.x) * 4;
  const void* src; long off;
  if      (i <  1572864) { src = s0; off = i; }
  else if (i <  3932160) { src = s1; off = i - 1572864; }
  else if (i <  6291456) { src = s2; off = i - 3932160; }
  else if (i <  8650752) { src = s3; off = i - 6291456; }
  else if (i < 11010048) { src = s4; off = i - 8650752; }
  else if (i < 15728640) { src = s5; off = i - 11010048; }
  else                   { src = s6; off = i - 15728640; }
  if (flags[0]) {
    *(ushort4*)(dst + i) = *((const ushort4*)((const ushort_t*)src + off));
  } else {
    float4 f = ((const float4*)src)[off >> 2];
    ushort4 o;
    o.x = f2bf(f.x); o.y = f2bf(f.y); o.z = f2bf(f.z); o.w = f2bf(f.w);
    *(ushort4*)(dst + i) = o;
  }
}

// biases -> fp32, [bs1|bs2|be1|be2|bo1|bo2|zeros] = 11520 + 3072 floats
__global__ void cvt_bias(const int* __restrict__ flags,
                         const void* b0, const void* b1, const void* b2,
                         const void* b3, const void* b4, const void* b5,
                         float* __restrict__ dst) {
  int i = blockIdx.x * 256 + threadIdx.x;
  if (i >= 14592) return;
  if (i >= 11520) { dst[i] = 0.f; return; }  // zero-bias tail
  const void* src; int off;
  if (i < 3072)       { src = b0; off = i; }
  else if (i < 3840)  { src = b1; off = i - 3072; }
  else if (i < 6912)  { src = b2; off = i - 3840; }
  else if (i < 7680)  { src = b3; off = i - 6912; }
  else if (i < 10752) { src = b4; off = i - 7680; }
  else                { src = b5; off = i - 10752; }
  dst[i] = flags[0] ? __bfloat162float(((const bf16*)src)[off])
                    : ((const float*)src)[off];
}

// C[M,N] = act(A[M,K] @ Bw[N,K(bstride)]^T + bias), A optionally gathered.
// Grid: (m-tiles, n-tiles) — m on blockIdx.x so same-A blocks (diff n) have
// linear ids differing by gridDim.x (mult of 8) -> same XCD -> A L2 reuse.
// Dual-launch: blocks with blockIdx.y >= nsplit use the second operand set.
// LDS k-block XOR swizzle kills the 8-way ds_read_b128 conflict.
template <bool GATHER, bool RELU, bool OUTF32>
__global__ __launch_bounds__(256) void gemm_bt(
    const bf16* __restrict__ A, const bf16* __restrict__ A2,
    const bf16* __restrict__ repS, const bf16* __restrict__ repE,
    const int* __restrict__ sidx, int row_base,
    const bf16* __restrict__ Bw, const bf16* __restrict__ Bw2,
    const float* __restrict__ bias, const float* __restrict__ bias2,
    void* __restrict__ C, void* __restrict__ C2, int nsplit,
    int N, int Kdim, int bstride) {
  __shared__ bf16 lA[BM * BK];
  __shared__ bf16 lB[BN * BK];

  const int tid  = threadIdx.x;
  const int lane = tid & 63;
  const int wave = tid >> 6;
  const int wm = wave >> 1, wn = wave & 1;
  int by = blockIdx.y;
  const bf16* Bw_ = Bw; const float* bias_ = bias; void* C_ = C; const bf16* A_ = A;
  if (by >= nsplit) { by -= nsplit; Bw_ = Bw2; bias_ = bias2; C_ = C2; A_ = A2; }
  const int m0 = blockIdx.x * BM;
  const int n0 = by * BN;

  const int srow = tid >> 2;
  const int scol = 8 * ((tid & 3) ^ ((tid >> 3) & 3));

  const bf16 *a0 = nullptr, *a1 = nullptr;
  const bf16 *pS0 = nullptr, *pE0 = nullptr, *pS1 = nullptr, *pE1 = nullptr;
  if (GATHER) {
    int r0 = row_base + m0 + srow;
    int r1 = r0 + 64;
    int b0 = r0 / 6144, b1 = r1 / 6144;
    int s0 = min(max(sidx[2 * r0], 0), 511);
    int e0 = min(max(sidx[2 * r0 + 1], 0), 511);
    int s1 = min(max(sidx[2 * r1], 0), 511);
    int e1 = min(max(sidx[2 * r1 + 1], 0), 511);
    pS0 = repS + ((size_t)b0 * 512 + s0) * 768 + scol;
    pE0 = repE + ((size_t)b0 * 512 + e0) * 768 + scol;
    pS1 = repS + ((size_t)b1 * 512 + s1) * 768 + scol;
    pE1 = repE + ((size_t)b1 * 512 + e1) * 768 + scol;
  } else {
    a0 = A_ + (size_t)(m0 + srow) * Kdim + scol;
    a1 = a0 + (size_t)64 * Kdim;
  }
  const bf16* b0p = Bw_ + (size_t)(n0 + srow) * bstride + scol;
  const bf16* b1p = b0p + (size_t)64 * bstride;

  f32x4 acc[4][4];
  const f32x4 z = {0.f, 0.f, 0.f, 0.f};
#pragma unroll
  for (int i = 0; i < 4; ++i)
#pragma unroll
    for (int j = 0; j < 4; ++j) acc[i][j] = z;

  const int fr = lane & 15;
  const int fk = 8 * ((lane >> 4) ^ ((lane >> 1) & 3));

  for (int k0 = 0; k0 < Kdim; k0 += BK) {
    const bf16 *sa0, *sa1;
    if (GATHER) {
      if (k0 < 768) { sa0 = pS0 + k0; sa1 = pS1 + k0; }
      else          { sa0 = pE0 + (k0 - 768); sa1 = pE1 + (k0 - 768); }
    } else {
      sa0 = a0 + k0; sa1 = a1 + k0;
    }
    gl_lds16(sa0, lA + tid * 8);
    gl_lds16(sa1, lA + 2048 + tid * 8);
    gl_lds16(b0p + k0, lB + tid * 8);
    gl_lds16(b1p + k0, lB + 2048 + tid * 8);
    __syncthreads();

    bf16x8 af[4], bv[4];
#pragma unroll
    for (int i = 0; i < 4; ++i)
      af[i] = *(const bf16x8*)(const void*)(lA + (wm * 64 + i * 16 + fr) * BK + fk);
#pragma unroll
    for (int j = 0; j < 4; ++j)
      bv[j] = *(const bf16x8*)(const void*)(lB + (wn * 64 + j * 16 + fr) * BK + fk);
#pragma unroll
    for (int i = 0; i < 4; ++i)
#pragma unroll
      for (int j = 0; j < 4; ++j)
        acc[i][j] = __builtin_amdgcn_mfma_f32_16x16x32_bf16(af[i], bv[j], acc[i][j], 0, 0, 0);
    __syncthreads();
  }

  float* Cf = (float*)C_;
  bf16*  Cb = (bf16*)C_;
#pragma unroll
  for (int j = 0; j < 4; ++j) {
    int n = n0 + wn * 64 + j * 16 + fr;
    float bj = bias_[n];
#pragma unroll
    for (int i = 0; i < 4; ++i) {
      int mb = m0 + wm * 64 + i * 16 + (lane >> 4) * 4;
#pragma unroll
      for (int r = 0; r < 4; ++r) {
        float v = acc[i][j][r] + bj;
        if (RELU) v = fmaxf(v, 0.f);
        if (OUTF32) Cf[(size_t)(mb + r) * N + n] = v;
        else        Cb[(size_t)(mb + r) * N + n] = __float2bfloat16(v);
      }
    }
  }
}

// Final GEMM, fused gather-add-relu A-staging.
//   A[r][k] = relu(Ps[tok_s(r)][k] + Pe[tok_e(r)][k]),  out = A @ wo2^T + bo2
// Ps/Pe [2048][3072] bf16. N=768, K=3072.
// v9 = v8 with the staging ADDRESSING fixed (v8 failed correctness).
// Rule-#21 bug in v8: (a) B staging put the XOR swizzle in the LDS dest of
// global_load_lds — but gl_lds writes wave-uniform-base + lane*16 LINEARLY,
// ignoring per-lane LDS addresses, so data landed linear while the reader
// expected swizzled; (b) A pack_store wrote swizzled-dest from swizzled-
// source (double-swizzle = identity) vs swizzled reader. Fix: LDS dests are
// LINEAR in t8 (aoff/boff = t8*8), swizzle lives ONLY in the global source
// pointers (the proven v7/m173 pattern). Since t8*8 == srow*32 + (t8&3)*8,
// LDS[srow][c] holds global col c^((srow>>1)&3) — exactly what the
// fragment reader (fk = 8*((lane>>4)^((lane>>1)&3))) expects.
// Structure (unchanged from v8's intent): BM=64 x BN=256 x BK=64, 512 thr,
// grid (384,3): 48 steps (half of v7's 96), 16 MFMA/wave/step, LDS 80KB
// (A 2x8KB + B 2x32KB) -> 2 blocks/CU.
__global__ __launch_bounds__(512) void gemm_final_fused(
    const ushort_t* __restrict__ Ps, const ushort_t* __restrict__ Pe,
    const int* __restrict__ sidx,
    const bf16* __restrict__ Bw, const float* __restrict__ bias,
    float* __restrict__ out) {
  __shared__ bf16 lA[2 * 4096];   // 16 KB: two 64x64 A buffers (2 k-subtiles of 64x32)
  __shared__ bf16 lB[2 * 16384];  // 64 KB: two 256x64 B buffers (2 k-subtiles of 256x32)

  const int tid  = threadIdx.x;   // 512 threads
  const int lane = tid & 63;
  const int wave = tid >> 6;      // 8 waves: 2m x 4n
  const int wm = wave >> 2, wn = wave & 3;  // wave tile 32m x 64n
  const int m0 = blockIdx.x * 64;
  const int n0 = blockIdx.y * 256;

  const int t8   = tid & 255;
  const int ksub = tid >> 8;                          // k-subtile 0/1 (wave-uniform)
  const int srow = t8 >> 2;                           // [0,64)
  const int scol = 8 * ((t8 & 3) ^ ((t8 >> 3) & 3));  // swizzled col (GLOBAL side only)

  // A gather: thread stages 16B of row (m0+srow), global k-col ksub*32+scol(+k0)
  int r0 = m0 + srow;
  int b0 = r0 / 6144;
  int s0 = min(max(sidx[2 * r0], 0), 511);
  int e0 = min(max(sidx[2 * r0 + 1], 0), 511);
  const ushort_t* pS0 = Ps + ((size_t)b0 * 512 + s0) * 3072 + ksub * 32 + scol;
  const ushort_t* pE0 = Pe + ((size_t)b0 * 512 + e0) * 3072 + ksub * 32 + scol;
  const int aoff = ksub * 2048 + t8 * 8;   // LINEAR LDS dest (rule #21)

  // B staging: thread covers k-subtile ksub, rows srow + {0,64,128,192}
  const bf16* bp = Bw + (size_t)(n0 + srow) * 3072 + ksub * 32 + scol;
  const int boff = ksub * 8192 + t8 * 8;   // LINEAR LDS dest; g adds g*2048

  f32x4 acc[2][4];
  const f32x4 z = {0.f, 0.f, 0.f, 0.f};
#pragma unroll
  for (int i = 0; i < 2; ++i)
#pragma unroll
    for (int j = 0; j < 4; ++j) acc[i][j] = z;

  const int fr = lane & 15;
  const int fk = 8 * ((lane >> 4) ^ ((lane >> 1) & 3));

  // pack one gathered row chunk pair -> relu'd bf16x8 -> LDS
  auto pack_store = [&](u32x4 xs, u32x4 xe, bf16* dst) {
    u32x4 wv;
#pragma unroll
    for (int q = 0; q < 4; ++q) {
      float lo = fmaxf(__uint_as_float(xs[q] << 16) + __uint_as_float(xe[q] << 16), 0.f);
      float hi = fmaxf(__uint_as_float(xs[q] & 0xFFFF0000u) +
                       __uint_as_float(xe[q] & 0xFFFF0000u), 0.f);
      unsigned w;
      asm("v_cvt_pk_bf16_f32 %0, %1, %2" : "=v"(w) : "v"(lo), "v"(hi));
      wv[q] = w;
    }
    *(u32x4*)(void*)dst = wv;
  };

  auto stageB = [&](int k0, int buf) {  // buf = element offset of target buffer
#pragma unroll
    for (int g = 0; g < 4; ++g)
      gl_lds16(bp + (size_t)g * 64 * 3072 + k0, lB + buf + boff + g * 2048);
  };

  // ---- prologue: stage tile 0 into buffer 0 ----
  {
    stageB(0, 0);
    u32x4 xs = *(const u32x4*)(const void*)pS0;
    u32x4 xe = *(const u32x4*)(const void*)pE0;
    pack_store(xs, xe, lA + aoff);
    __syncthreads();
  }

  for (int it = 0; it < 48; ++it) {
    const int curA = (it & 1) << 12;   // 4096-element A buffers
    const int curB = (it & 1) << 14;   // 16384-element B buffers
    const int nxtA = curA ^ 4096;
    const int nxtB = curB ^ 16384;
    const int k1 = (it + 1) * 64;
    const bool pre = (it + 1) < 48;
    u32x4 xs, xe;
    if (pre) {  // issue next tile's loads BEFORE the MFMA block
      stageB(k1, nxtB);
      xs = *(const u32x4*)(const void*)(pS0 + k1);
      xe = *(const u32x4*)(const void*)(pE0 + k1);
    }

#pragma unroll
    for (int s = 0; s < 2; ++s) {
      bf16x8 af[2];
#pragma unroll
      for (int i = 0; i < 2; ++i)
        af[i] = *(const bf16x8*)(const void*)(
            lA + curA + s * 2048 + (wm * 32 + i * 16 + fr) * 32 + fk);
#pragma unroll
      for (int j = 0; j < 4; ++j) {
        bf16x8 bv = *(const bf16x8*)(const void*)(
            lB + curB + s * 8192 + (wn * 64 + j * 16 + fr) * 32 + fk);
#pragma unroll
        for (int i = 0; i < 2; ++i)
          acc[i][j] = __builtin_amdgcn_mfma_f32_16x16x32_bf16(af[i], bv, acc[i][j], 0, 0, 0);
      }
    }

    if (pre) {  // wait (compiler-counted vmcnt), pack, store
      pack_store(xs, xe, lA + nxtA + aoff);
    }
    __syncthreads();
  }

#pragma unroll
  for (int j = 0; j < 4; ++j) {
    int n = n0 + wn * 64 + j * 16 + fr;
    float bj = bias[n];
#pragma unroll
    for (int i = 0; i < 2; ++i) {
      int mb = m0 + wm * 32 + i * 16 + (lane >> 4) * 4;
#pragma unroll
      for (int r = 0; r < 4; ++r)
        out[(size_t)(mb + r) * 768 + n] = acc[i][j][r] + bj;
    }
  }
}

extern "C" void kernel_launch(void* const* d_in, const int* in_sizes, int n_in,
                              void* d_out, int out_size, void* d_ws, size_t ws_size,
                              hipStream_t stream) {
  const void* h    = d_in[0];
  const void* sidx = d_in[1];
  const void *ws1 = d_in[2],  *bs1 = d_in[3];
  const void *ws2 = d_in[4],  *bs2 = d_in[5];
  const void *we1 = d_in[6],  *be1 = d_in[7];
  const void *we2 = d_in[8],  *be2 = d_in[9];
  const void *wo1 = d_in[10], *bo1 = d_in[11];
  const void *wo2 = d_in[12], *bo2 = d_in[13];

  // ---- fixed workspace region ----
  char* p = (char*)d_ws;
  int*      flags = (int*)p;
  int*      idx32 = (int*)(p + 256);
  float*    biasf = (float*)(p + 256 + 196608);            // 14592 f32 (incl zeros)
  ushort_t* hb    = (ushort_t*)(p + 256 + 196608 + 65536);
  ushort_t* w1sb  = hb   + (size_t)1572864;
  ushort_t* w2sb  = w1sb + (size_t)2359296;
  ushort_t* w1eb  = w2sb + (size_t)2359296;
  ushort_t* w2eb  = w1eb + (size_t)2359296;
  ushort_t* wo1b  = w2eb + (size_t)2359296;
  ushort_t* wo2b  = wo1b + (size_t)4718592;
  ushort_t* repS  = wo2b + (size_t)2359296;
  ushort_t* repE  = repS + (size_t)1572864;
  char*     R     = (char*)(repE + (size_t)1572864);  // transient region
  size_t fixed = (size_t)(R - (char*)d_ws);
  if (ws_size < fixed) return;
  size_t Rsz = ws_size - fixed;

  const size_t P_BF = (size_t)2 * 2048 * 3072 * 2;  // Ps+Pe bf16 (== phase-A hid)
  int tier = (Rsz >= P_BF) ? 2 : 3;

  dim3 blk(256);
  const int XBIG = 0x40000000;
  sniff<<<1, blk, 0, stream>>>((const unsigned*)ws1, (const unsigned*)sidx, flags);
  norm_idx<<<192, blk, 0, stream>>>(flags, sidx, idx32);
  cvt_all<<<17664, blk, 0, stream>>>(flags, h, ws1, ws2, we1, we2, wo1, wo2, hb);
  cvt_bias<<<57, blk, 0, stream>>>(flags, bs1, bs2, be1, be2, bo1, bo2, biasf);
  const float *bs1f = biasf, *bs2f = biasf + 3072, *be1f = biasf + 3840,
              *be2f = biasf + 6912, *bo1f = biasf + 7680, *bo2f = biasf + 10752,
              *zerof = biasf + 11520;
  float* outf = (float*)d_out;

  if (tier == 2) {
    // Phase A: token MLPs (start+end merged), hid scratch in R (dead after)
    ushort_t* hidS = (ushort_t*)R;
    ushort_t* hidE = hidS + (size_t)2048 * 3072;
    gemm_bt<false, true, false><<<dim3(16, 48), blk, 0, stream>>>(
        (const bf16*)hb, (const bf16*)hb, nullptr, nullptr, nullptr, 0,
        (const bf16*)w1sb, (const bf16*)w1eb, bs1f, be1f,
        hidS, hidE, 24, 3072, 768, 768);
    gemm_bt<false, true, false><<<dim3(16, 12), blk, 0, stream>>>(
        (const bf16*)hidS, (const bf16*)hidE, nullptr, nullptr, nullptr, 0,
        (const bf16*)w2sb, (const bf16*)w2eb, bs2f, be2f,
        (bf16*)repS, (bf16*)repE, 6, 768, 3072, 3072);
    // Phase B': P_s = repS@wo1[:, :768]^T + bo1 ; P_e = repE@wo1[:, 768:]^T
    ushort_t* Ps = (ushort_t*)R;
    ushort_t* Pe = Ps + (size_t)2048 * 3072;
    gemm_bt<false, false, false><<<dim3(16, 48), blk, 0, stream>>>(
        (const bf16*)repS, (const bf16*)repE, nullptr, nullptr, nullptr, 0,
        (const bf16*)wo1b, (const bf16*)wo1b + 768, bo1f, zerof,
        Ps, Pe, 24, 3072, 768, 1536);
    gemm_final_fused<<<dim3(384, 3), dim3(512), 0, stream>>>(
        Ps, Pe, idx32, (const bf16*)wo2b, bo2f, outf);
  } else {
    // Tier 3 fallback: two-pass path, chunked in R
    long long cT = (long long)(Rsz / ((size_t)2 * 3072 * 2));
    cT = (cT / 128) * 128; if (cT > 2048) cT = 2048;
    long long cO = (long long)(Rsz / ((size_t)3072 * 2));
    cO = (cO / 128) * 128; if (cO > 24576) cO = 24576;
    if (cT < 128 || cO < 128) return;
    ushort_t* scr = (ushort_t*)R;
    for (long long r = 0; r < 2048; r += cT) {
      long long mc = 2048 - r < cT ? 2048 - r : cT;
      ushort_t* hidS = scr;
      ushort_t* hidE = scr + (size_t)cT * 3072;
      gemm_bt<false, true, false><<<dim3(mc / 128, 48), blk, 0, stream>>>(
          (const bf16*)hb + r * 768, (const bf16*)hb + r * 768,
          nullptr, nullptr, nullptr, 0,
          (const bf16*)w1sb, (const bf16*)w1eb, bs1f, be1f,
          hidS, hidE, 24, 3072, 768, 768);
      gemm_bt<false, true, false><<<dim3(mc / 128, 12), blk, 0, stream>>>(
          (const bf16*)hidS, (const bf16*)hidE, nullptr, nullptr, nullptr, 0,
          (const bf16*)w2sb, (const bf16*)w2eb, bs2f, be2f,
          (bf16*)repS + r * 768, (bf16*)repE + r * 768, 6, 768, 3072, 3072);
    }
    for (long long r = 0; r < 24576; r += cO) {
      long long mc = 24576 - r < cO ? 24576 - r : cO;
      gemm_bt<true, true, false><<<dim3(mc / 128, 24), blk, 0, stream>>>(
          nullptr, nullptr, (const bf16*)repS, (const bf16*)repE, idx32, (int)r,
          (const bf16*)wo1b, nullptr, bo1f, nullptr,
          scr, nullptr, XBIG, 3072, 1536, 1536);
      gemm_bt<false, false, true><<<dim3(mc / 128, 6), blk, 0, stream>>>(
          (const bf16*)scr, nullptr, nullptr, nullptr, nullptr, 0,
          (const bf16*)wo2b, nullptr, bo2f, nullptr,
          outf + (size_t)r * 768, nullptr, XBIG, 768, 3072, 3072);
    }
  }
}

// Round 10
// 474.189 us; speedup vs baseline: 1.0419x; 1.0419x over previous
//
#include <hip/hip_runtime.h>
#include <hip/hip_bf16.h>

using bf16 = __hip_bfloat16;
using bf16x8 = __attribute__((ext_vector_type(8))) __bf16;
using f32x4  = __attribute__((ext_vector_type(4))) float;
using u32x4  = __attribute__((ext_vector_type(4))) unsigned;
typedef unsigned short ushort_t;

#define BM 128
#define BN 128
#define BK 32

// B=4, L=512, D=768, W=12, K_spans=6144, rows_out = B*K = 24576

__device__ __forceinline__ void gl_lds16(const void* g, void* l) {
  __builtin_amdgcn_global_load_lds(
      (const __attribute__((address_space(1))) void*)g,
      (__attribute__((address_space(3))) void*)l, 16, 0, 0);
}

__device__ __forceinline__ ushort_t f2bf(float f) {  // RNE fp32->bf16
  unsigned u = __float_as_uint(f);
  u += 0x7FFF + ((u >> 16) & 1);
  return (ushort_t)(u >> 16);
}

// flags[0]=1 if float inputs are stored as bf16 (else fp32)
// flags[1]=1 if span_idx is int64 (else int32)
__global__ void sniff(const unsigned* __restrict__ w1,
                      const unsigned* __restrict__ idx, int* flags) {
  __shared__ int cnt[2];
  if (threadIdx.x == 0) { cnt[0] = 0; cnt[1] = 0; }
  __syncthreads();
  int t = threadIdx.x;  // 256 threads
  int c0 = 0;
  for (int k = 0; k < 4; ++k) {
    unsigned lo = w1[t * 4 + k] & 0xFFFFu;
    unsigned e = (lo >> 7) & 0xFF;
    if (e <= 122) c0++;
  }
  int c1 = (idx[2 * t + 1] != 0) ? 1 : 0;
  atomicAdd(&cnt[0], c0);
  atomicAdd(&cnt[1], c1);
  __syncthreads();
  if (threadIdx.x == 0) {
    flags[0] = (cnt[0] >= 900) ? 1 : 0;
    flags[1] = (cnt[1] == 0) ? 1 : 0;
  }
}

__global__ void norm_idx(const int* __restrict__ flags, const void* __restrict__ src,
                         int* __restrict__ dst) {
  int i = blockIdx.x * 256 + threadIdx.x;  // grid covers exactly 49152
  int v = flags[1] ? (int)((const long long*)src)[i] : ((const int*)src)[i];
  dst[i] = v;
}

// One kernel converts h + all 6 weights into the contiguous bf16 region at dst.
__global__ void cvt_all(const int* __restrict__ flags,
                        const void* s0, const void* s1, const void* s2,
                        const void* s3, const void* s4, const void* s5,
                        const void* s6, ushort_t* __restrict__ dst) {
  long i = ((long)blockIdx.x * 256 + threadIdx.x) * 4;
  const void* src; long off;
  if      (i <  1572864) { src = s0; off = i; }
  else if (i <  3932160) { src = s1; off = i - 1572864; }
  else if (i <  6291456) { src = s2; off = i - 3932160; }
  else if (i <  8650752) { src = s3; off = i - 6291456; }
  else if (i < 11010048) { src = s4; off = i - 8650752; }
  else if (i < 15728640) { src = s5; off = i - 11010048; }
  else                   { src = s6; off = i - 15728640; }
  if (flags[0]) {
    *(ushort4*)(dst + i) = *((const ushort4*)((const ushort_t*)src + off));
  } else {
    float4 f = ((const float4*)src)[off >> 2];
    ushort4 o;
    o.x = f2bf(f.x); o.y = f2bf(f.y); o.z = f2bf(f.z); o.w = f2bf(f.w);
    *(ushort4*)(dst + i) = o;
  }
}

// biases -> fp32, [bs1|bs2|be1|be2|bo1|bo2|zeros] = 11520 + 3072 floats
__global__ void cvt_bias(const int* __restrict__ flags,
                         const void* b0, const void* b1, const void* b2,
                         const void* b3, const void* b4, const void* b5,
                         float* __restrict__ dst) {
  int i = blockIdx.x * 256 + threadIdx.x;
  if (i >= 14592) return;
  if (i >= 11520) { dst[i] = 0.f; return; }  // zero-bias tail
  const void* src; int off;
  if (i < 3072)       { src = b0; off = i; }
  else if (i < 3840)  { src = b1; off = i - 3072; }
  else if (i < 6912)  { src = b2; off = i - 3840; }
  else if (i < 7680)  { src = b3; off = i - 6912; }
  else if (i < 10752) { src = b4; off = i - 7680; }
  else                { src = b5; off = i - 10752; }
  dst[i] = flags[0] ? __bfloat162float(((const bf16*)src)[off])
                    : ((const float*)src)[off];
}

// C[M,N] = act(A[M,K] @ Bw[N,K(bstride)]^T + bias), A optionally gathered.
// Grid: (m-tiles, n-tiles) — m on blockIdx.x so same-A blocks (diff n) have
// linear ids differing by gridDim.x (mult of 8) -> same XCD -> A L2 reuse.
// Dual-launch: blocks with blockIdx.y >= nsplit use the second operand set.
// LDS k-block XOR swizzle kills the 8-way ds_read_b128 conflict.
template <bool GATHER, bool RELU, bool OUTF32>
__global__ __launch_bounds__(256) void gemm_bt(
    const bf16* __restrict__ A, const bf16* __restrict__ A2,
    const bf16* __restrict__ repS, const bf16* __restrict__ repE,
    const int* __restrict__ sidx, int row_base,
    const bf16* __restrict__ Bw, const bf16* __restrict__ Bw2,
    const float* __restrict__ bias, const float* __restrict__ bias2,
    void* __restrict__ C, void* __restrict__ C2, int nsplit,
    int N, int Kdim, int bstride) {
  __shared__ bf16 lA[BM * BK];
  __shared__ bf16 lB[BN * BK];

  const int tid  = threadIdx.x;
  const int lane = tid & 63;
  const int wave = tid >> 6;
  const int wm = wave >> 1, wn = wave & 1;
  int by = blockIdx.y;
  const bf16* Bw_ = Bw; const float* bias_ = bias; void* C_ = C; const bf16* A_ = A;
  if (by >= nsplit) { by -= nsplit; Bw_ = Bw2; bias_ = bias2; C_ = C2; A_ = A2; }
  const int m0 = blockIdx.x * BM;
  const int n0 = by * BN;

  const int srow = tid >> 2;
  const int scol = 8 * ((tid & 3) ^ ((tid >> 3) & 3));

  const bf16 *a0 = nullptr, *a1 = nullptr;
  const bf16 *pS0 = nullptr, *pE0 = nullptr, *pS1 = nullptr, *pE1 = nullptr;
  if (GATHER) {
    int r0 = row_base + m0 + srow;
    int r1 = r0 + 64;
    int b0 = r0 / 6144, b1 = r1 / 6144;
    int s0 = min(max(sidx[2 * r0], 0), 511);
    int e0 = min(max(sidx[2 * r0 + 1], 0), 511);
    int s1 = min(max(sidx[2 * r1], 0), 511);
    int e1 = min(max(sidx[2 * r1 + 1], 0), 511);
    pS0 = repS + ((size_t)b0 * 512 + s0) * 768 + scol;
    pE0 = repE + ((size_t)b0 * 512 + e0) * 768 + scol;
    pS1 = repS + ((size_t)b1 * 512 + s1) * 768 + scol;
    pE1 = repE + ((size_t)b1 * 512 + e1) * 768 + scol;
  } else {
    a0 = A_ + (size_t)(m0 + srow) * Kdim + scol;
    a1 = a0 + (size_t)64 * Kdim;
  }
  const bf16* b0p = Bw_ + (size_t)(n0 + srow) * bstride + scol;
  const bf16* b1p = b0p + (size_t)64 * bstride;

  f32x4 acc[4][4];
  const f32x4 z = {0.f, 0.f, 0.f, 0.f};
#pragma unroll
  for (int i = 0; i < 4; ++i)
#pragma unroll
    for (int j = 0; j < 4; ++j) acc[i][j] = z;

  const int fr = lane & 15;
  const int fk = 8 * ((lane >> 4) ^ ((lane >> 1) & 3));

  for (int k0 = 0; k0 < Kdim; k0 += BK) {
    const bf16 *sa0, *sa1;
    if (GATHER) {
      if (k0 < 768) { sa0 = pS0 + k0; sa1 = pS1 + k0; }
      else          { sa0 = pE0 + (k0 - 768); sa1 = pE1 + (k0 - 768); }
    } else {
      sa0 = a0 + k0; sa1 = a1 + k0;
    }
    gl_lds16(sa0, lA + tid * 8);
    gl_lds16(sa1, lA + 2048 + tid * 8);
    gl_lds16(b0p + k0, lB + tid * 8);
    gl_lds16(b1p + k0, lB + 2048 + tid * 8);
    __syncthreads();

    bf16x8 af[4], bv[4];
#pragma unroll
    for (int i = 0; i < 4; ++i)
      af[i] = *(const bf16x8*)(const void*)(lA + (wm * 64 + i * 16 + fr) * BK + fk);
#pragma unroll
    for (int j = 0; j < 4; ++j)
      bv[j] = *(const bf16x8*)(const void*)(lB + (wn * 64 + j * 16 + fr) * BK + fk);
#pragma unroll
    for (int i = 0; i < 4; ++i)
#pragma unroll
      for (int j = 0; j < 4; ++j)
        acc[i][j] = __builtin_amdgcn_mfma_f32_16x16x32_bf16(af[i], bv[j], acc[i][j], 0, 0, 0);
    __syncthreads();
  }

  float* Cf = (float*)C_;
  bf16*  Cb = (bf16*)C_;
#pragma unroll
  for (int j = 0; j < 4; ++j) {
    int n = n0 + wn * 64 + j * 16 + fr;
    float bj = bias_[n];
#pragma unroll
    for (int i = 0; i < 4; ++i) {
      int mb = m0 + wm * 64 + i * 16 + (lane >> 4) * 4;
#pragma unroll
      for (int r = 0; r < 4; ++r) {
        float v = acc[i][j][r] + bj;
        if (RELU) v = fmaxf(v, 0.f);
        if (OUTF32) Cf[(size_t)(mb + r) * N + n] = v;
        else        Cb[(size_t)(mb + r) * N + n] = __float2bfloat16(v);
      }
    }
  }
}

// 64x64-tile GEMM for the hid->rep stage (M=2048, N=768/set, K=3072, dual).
// The 128x128 gemm_bt gives only dim(16,12)=192 blocks = 0.75/CU for this
// shape — a quarter of the machine idle with zero cross-block latency
// hiding over 96 K-steps. 64x64 -> dim(32,24)=768 blocks (3/CU), 8 KB LDS,
// ~8 blocks/CU resident possible: latency hidden by TLP.
// Same staging/swizzle/fragment math as gemm_bt (srow spans 64 rows).
// rep = relu(hid @ w2^T + b2), output bf16.
__global__ __launch_bounds__(256) void gemm_bt64(
    const bf16* __restrict__ A, const bf16* __restrict__ A2,
    const bf16* __restrict__ Bw, const bf16* __restrict__ Bw2,
    const float* __restrict__ bias, const float* __restrict__ bias2,
    bf16* __restrict__ C, bf16* __restrict__ C2, int nsplit,
    int N, int Kdim) {
  __shared__ bf16 lA[64 * BK];   // 4 KB
  __shared__ bf16 lB[64 * BK];   // 4 KB

  const int tid  = threadIdx.x;
  const int lane = tid & 63;
  const int wave = tid >> 6;          // 4 waves: 2m x 2n, wave tile 32x32
  const int wm = wave >> 1, wn = wave & 1;
  int by = blockIdx.y;
  const bf16* Bw_ = Bw; const float* bias_ = bias; bf16* C_ = C; const bf16* A_ = A;
  if (by >= nsplit) { by -= nsplit; Bw_ = Bw2; bias_ = bias2; C_ = C2; A_ = A2; }
  const int m0 = blockIdx.x * 64;
  const int n0 = by * 64;

  const int srow = tid >> 2;                          // [0,64)
  const int scol = 8 * ((tid & 3) ^ ((tid >> 3) & 3));

  const bf16* ap = A_  + (size_t)(m0 + srow) * Kdim + scol;
  const bf16* bp = Bw_ + (size_t)(n0 + srow) * Kdim + scol;

  f32x4 acc[2][2];
  const f32x4 z = {0.f, 0.f, 0.f, 0.f};
#pragma unroll
  for (int i = 0; i < 2; ++i)
#pragma unroll
    for (int j = 0; j < 2; ++j) acc[i][j] = z;

  const int fr = lane & 15;
  const int fk = 8 * ((lane >> 4) ^ ((lane >> 1) & 3));

  for (int k0 = 0; k0 < Kdim; k0 += BK) {
    gl_lds16(ap + k0, lA + tid * 8);
    gl_lds16(bp + k0, lB + tid * 8);
    __syncthreads();

    bf16x8 af[2], bv[2];
#pragma unroll
    for (int i = 0; i < 2; ++i)
      af[i] = *(const bf16x8*)(const void*)(lA + (wm * 32 + i * 16 + fr) * BK + fk);
#pragma unroll
    for (int j = 0; j < 2; ++j)
      bv[j] = *(const bf16x8*)(const void*)(lB + (wn * 32 + j * 16 + fr) * BK + fk);
#pragma unroll
    for (int i = 0; i < 2; ++i)
#pragma unroll
      for (int j = 0; j < 2; ++j)
        acc[i][j] = __builtin_amdgcn_mfma_f32_16x16x32_bf16(af[i], bv[j], acc[i][j], 0, 0, 0);
    __syncthreads();
  }

#pragma unroll
  for (int j = 0; j < 2; ++j) {
    int n = n0 + wn * 32 + j * 16 + fr;
    float bj = bias_[n];
#pragma unroll
    for (int i = 0; i < 2; ++i) {
      int mb = m0 + wm * 32 + i * 16 + (lane >> 4) * 4;
#pragma unroll
      for (int r = 0; r < 4; ++r) {
        float v = fmaxf(acc[i][j][r] + bj, 0.f);
        C_[(size_t)(mb + r) * N + n] = __float2bfloat16(v);
      }
    }
  }
}

// Final GEMM, fused gather-add-relu A-staging.
//   A[r][k] = relu(Ps[tok_s(r)][k] + Pe[tok_e(r)][k]),  out = A @ wo2^T + bo2
// Ps/Pe [2048][3072] bf16. N=768, K=3072.
// v10 = v9 + A-loads issued BEFORE stageB. In v9's order (B first, A last)
// the compiler's wait for the pack's A operands is effectively vmcnt(0) —
// in-order retirement means waiting for the last-issued loads (A) drains
// the just-issued B gl_lds too, serializing the B prefetch at the pack
// point. A-first makes the A-wait vmcnt(4): B(t+1) stays in flight through
// the pack and is only drained at the (inevitable) __syncthreads.
// Structure otherwise v9: BM=64 x BN=256 x BK=64, 512 thr, grid (384,3),
// 48 steps, LDS 80KB -> 2 blocks/CU. Linear LDS dests, swizzle on the
// global side only (rule #21).
__global__ __launch_bounds__(512) void gemm_final_fused(
    const ushort_t* __restrict__ Ps, const ushort_t* __restrict__ Pe,
    const int* __restrict__ sidx,
    const bf16* __restrict__ Bw, const float* __restrict__ bias,
    float* __restrict__ out) {
  __shared__ bf16 lA[2 * 4096];   // 16 KB: two 64x64 A buffers (2 k-subtiles of 64x32)
  __shared__ bf16 lB[2 * 16384];  // 64 KB: two 256x64 B buffers (2 k-subtiles of 256x32)

  const int tid  = threadIdx.x;   // 512 threads
  const int lane = tid & 63;
  const int wave = tid >> 6;      // 8 waves: 2m x 4n
  const int wm = wave >> 2, wn = wave & 3;  // wave tile 32m x 64n
  const int m0 = blockIdx.x * 64;
  const int n0 = blockIdx.y * 256;

  const int t8   = tid & 255;
  const int ksub = tid >> 8;                          // k-subtile 0/1 (wave-uniform)
  const int srow = t8 >> 2;                           // [0,64)
  const int scol = 8 * ((t8 & 3) ^ ((t8 >> 3) & 3));  // swizzled col (GLOBAL side only)

  // A gather: thread stages 16B of row (m0+srow), global k-col ksub*32+scol(+k0)
  int r0 = m0 + srow;
  int b0 = r0 / 6144;
  int s0 = min(max(sidx[2 * r0], 0), 511);
  int e0 = min(max(sidx[2 * r0 + 1], 0), 511);
  const ushort_t* pS0 = Ps + ((size_t)b0 * 512 + s0) * 3072 + ksub * 32 + scol;
  const ushort_t* pE0 = Pe + ((size_t)b0 * 512 + e0) * 3072 + ksub * 32 + scol;
  const int aoff = ksub * 2048 + t8 * 8;   // LINEAR LDS dest (rule #21)

  // B staging: thread covers k-subtile ksub, rows srow + {0,64,128,192}
  const bf16* bp = Bw + (size_t)(n0 + srow) * 3072 + ksub * 32 + scol;
  const int boff = ksub * 8192 + t8 * 8;   // LINEAR LDS dest; g adds g*2048

  f32x4 acc[2][4];
  const f32x4 z = {0.f, 0.f, 0.f, 0.f};
#pragma unroll
  for (int i = 0; i < 2; ++i)
#pragma unroll
    for (int j = 0; j < 4; ++j) acc[i][j] = z;

  const int fr = lane & 15;
  const int fk = 8 * ((lane >> 4) ^ ((lane >> 1) & 3));

  // pack one gathered row chunk pair -> relu'd bf16x8 -> LDS
  auto pack_store = [&](u32x4 xs, u32x4 xe, bf16* dst) {
    u32x4 wv;
#pragma unroll
    for (int q = 0; q < 4; ++q) {
      float lo = fmaxf(__uint_as_float(xs[q] << 16) + __uint_as_float(xe[q] << 16), 0.f);
      float hi = fmaxf(__uint_as_float(xs[q] & 0xFFFF0000u) +
                       __uint_as_float(xe[q] & 0xFFFF0000u), 0.f);
      unsigned w;
      asm("v_cvt_pk_bf16_f32 %0, %1, %2" : "=v"(w) : "v"(lo), "v"(hi));
      wv[q] = w;
    }
    *(u32x4*)(void*)dst = wv;
  };

  auto stageB = [&](int k0, int buf) {  // buf = element offset of target buffer
#pragma unroll
    for (int g = 0; g < 4; ++g)
      gl_lds16(bp + (size_t)g * 64 * 3072 + k0, lB + buf + boff + g * 2048);
  };

  // ---- prologue: stage tile 0 into buffer 0 ----
  {
    u32x4 xs = *(const u32x4*)(const void*)pS0;
    u32x4 xe = *(const u32x4*)(const void*)pE0;
    stageB(0, 0);
    pack_store(xs, xe, lA + aoff);
    __syncthreads();
  }

  for (int it = 0; it < 48; ++it) {
    const int curA = (it & 1) << 12;   // 4096-element A buffers
    const int curB = (it & 1) << 14;   // 16384-element B buffers
    const int nxtA = curA ^ 4096;
    const int nxtB = curB ^ 16384;
    const int k1 = (it + 1) * 64;
    const bool pre = (it + 1) < 48;
    u32x4 xs, xe;
    if (pre) {  // A loads FIRST so their wait leaves B's gl_lds in flight
      xs = *(const u32x4*)(const void*)(pS0 + k1);
      xe = *(const u32x4*)(const void*)(pE0 + k1);
      stageB(k1, nxtB);
    }

#pragma unroll
    for (int s = 0; s < 2; ++s) {
      bf16x8 af[2];
#pragma unroll
      for (int i = 0; i < 2; ++i)
        af[i] = *(const bf16x8*)(const void*)(
            lA + curA + s * 2048 + (wm * 32 + i * 16 + fr) * 32 + fk);
#pragma unroll
      for (int j = 0; j < 4; ++j) {
        bf16x8 bv = *(const bf16x8*)(const void*)(
            lB + curB + s * 8192 + (wn * 64 + j * 16 + fr) * 32 + fk);
#pragma unroll
        for (int i = 0; i < 2; ++i)
          acc[i][j] = __builtin_amdgcn_mfma_f32_16x16x32_bf16(af[i], bv, acc[i][j], 0, 0, 0);
      }
    }

    if (pre) {  // wait (compiler-counted vmcnt(4)), pack, store
      pack_store(xs, xe, lA + nxtA + aoff);
    }
    __syncthreads();
  }

#pragma unroll
  for (int j = 0; j < 4; ++j) {
    int n = n0 + wn * 64 + j * 16 + fr;
    float bj = bias[n];
#pragma unroll
    for (int i = 0; i < 2; ++i) {
      int mb = m0 + wm * 32 + i * 16 + (lane >> 4) * 4;
#pragma unroll
      for (int r = 0; r < 4; ++r)
        out[(size_t)(mb + r) * 768 + n] = acc[i][j][r] + bj;
    }
  }
}

extern "C" void kernel_launch(void* const* d_in, const int* in_sizes, int n_in,
                              void* d_out, int out_size, void* d_ws, size_t ws_size,
                              hipStream_t stream) {
  const void* h    = d_in[0];
  const void* sidx = d_in[1];
  const void *ws1 = d_in[2],  *bs1 = d_in[3];
  const void *ws2 = d_in[4],  *bs2 = d_in[5];
  const void *we1 = d_in[6],  *be1 = d_in[7];
  const void *we2 = d_in[8],  *be2 = d_in[9];
  const void *wo1 = d_in[10], *bo1 = d_in[11];
  const void *wo2 = d_in[12], *bo2 = d_in[13];

  // ---- fixed workspace region ----
  char* p = (char*)d_ws;
  int*      flags = (int*)p;
  int*      idx32 = (int*)(p + 256);
  float*    biasf = (float*)(p + 256 + 196608);            // 14592 f32 (incl zeros)
  ushort_t* hb    = (ushort_t*)(p + 256 + 196608 + 65536);
  ushort_t* w1sb  = hb   + (size_t)1572864;
  ushort_t* w2sb  = w1sb + (size_t)2359296;
  ushort_t* w1eb  = w2sb + (size_t)2359296;
  ushort_t* w2eb  = w1eb + (size_t)2359296;
  ushort_t* wo1b  = w2eb + (size_t)2359296;
  ushort_t* wo2b  = wo1b + (size_t)4718592;
  ushort_t* repS  = wo2b + (size_t)2359296;
  ushort_t* repE  = repS + (size_t)1572864;
  char*     R     = (char*)(repE + (size_t)1572864);  // transient region
  size_t fixed = (size_t)(R - (char*)d_ws);
  if (ws_size < fixed) return;
  size_t Rsz = ws_size - fixed;

  const size_t P_BF = (size_t)2 * 2048 * 3072 * 2;  // Ps+Pe bf16 (== phase-A hid)
  int tier = (Rsz >= P_BF) ? 2 : 3;

  dim3 blk(256);
  const int XBIG = 0x40000000;
  sniff<<<1, blk, 0, stream>>>((const unsigned*)ws1, (const unsigned*)sidx, flags);
  norm_idx<<<192, blk, 0, stream>>>(flags, sidx, idx32);
  cvt_all<<<17664, blk, 0, stream>>>(flags, h, ws1, ws2, we1, we2, wo1, wo2, hb);
  cvt_bias<<<57, blk, 0, stream>>>(flags, bs1, bs2, be1, be2, bo1, bo2, biasf);
  const float *bs1f = biasf, *bs2f = biasf + 3072, *be1f = biasf + 3840,
              *be2f = biasf + 6912, *bo1f = biasf + 7680, *bo2f = biasf + 10752,
              *zerof = biasf + 11520;
  float* outf = (float*)d_out;

  if (tier == 2) {
    // Phase A: token MLPs (start+end merged), hid scratch in R (dead after)
    ushort_t* hidS = (ushort_t*)R;
    ushort_t* hidE = hidS + (size_t)2048 * 3072;
    gemm_bt<false, true, false><<<dim3(16, 48), blk, 0, stream>>>(
        (const bf16*)hb, (const bf16*)hb, nullptr, nullptr, nullptr, 0,
        (const bf16*)w1sb, (const bf16*)w1eb, bs1f, be1f,
        hidS, hidE, 24, 3072, 768, 768);
    gemm_bt64<<<dim3(32, 24), blk, 0, stream>>>(
        (const bf16*)hidS, (const bf16*)hidE,
        (const bf16*)w2sb, (const bf16*)w2eb, bs2f, be2f,
        (bf16*)repS, (bf16*)repE, 12, 768, 3072);
    // Phase B': P_s = repS@wo1[:, :768]^T + bo1 ; P_e = repE@wo1[:, 768:]^T
    ushort_t* Ps = (ushort_t*)R;
    ushort_t* Pe = Ps + (size_t)2048 * 3072;
    gemm_bt<false, false, false><<<dim3(16, 48), blk, 0, stream>>>(
        (const bf16*)repS, (const bf16*)repE, nullptr, nullptr, nullptr, 0,
        (const bf16*)wo1b, (const bf16*)wo1b + 768, bo1f, zerof,
        Ps, Pe, 24, 3072, 768, 1536);
    gemm_final_fused<<<dim3(384, 3), dim3(512), 0, stream>>>(
        Ps, Pe, idx32, (const bf16*)wo2b, bo2f, outf);
  } else {
    // Tier 3 fallback: two-pass path, chunked in R
    long long cT = (long long)(Rsz / ((size_t)2 * 3072 * 2));
    cT = (cT / 128) * 128; if (cT > 2048) cT = 2048;
    long long cO = (long long)(Rsz / ((size_t)3072 * 2));
    cO = (cO / 128) * 128; if (cO > 24576) cO = 24576;
    if (cT < 128 || cO < 128) return;
    ushort_t* scr = (ushort_t*)R;
    for (long long r = 0; r < 2048; r += cT) {
      long long mc = 2048 - r < cT ? 2048 - r : cT;
      ushort_t* hidS = scr;
      ushort_t* hidE = scr + (size_t)cT * 3072;
      gemm_bt<false, true, false><<<dim3(mc / 128, 48), blk, 0, stream>>>(
          (const bf16*)hb + r * 768, (const bf16*)hb + r * 768,
          nullptr, nullptr, nullptr, 0,
          (const bf16*)w1sb, (const bf16*)w1eb, bs1f, be1f,
          hidS, hidE, 24, 3072, 768, 768);
      gemm_bt<false, true, false><<<dim3(mc / 128, 12), blk, 0, stream>>>(
          (const bf16*)hidS, (const bf16*)hidE, nullptr, nullptr, nullptr, 0,
          (const bf16*)w2sb, (const bf16*)w2eb, bs2f, be2f,
          (bf16*)repS + r * 768, (bf16*)repE + r * 768, 6, 768, 3072, 3072);
    }
    for (long long r = 0; r < 24576; r += cO) {
      long long mc = 24576 - r < cO ? 24576 - r : cO;
      gemm_bt<true, true, false><<<dim3(mc / 128, 24), blk, 0, stream>>>(
          nullptr, nullptr, (const bf16*)repS, (const bf16*)repE, idx32, (int)r,
          (const bf16*)wo1b, nullptr, bo1f, nullptr,
          scr, nullptr, XBIG, 3072, 1536, 1536);
      gemm_bt<false, false, true><<<dim3(mc / 128, 6), blk, 0, stream>>>(
          (const bf16*)scr, nullptr, nullptr, nullptr, nullptr, 0,
          (const bf16*)wo2b, nullptr, bo2f, nullptr,
          outf + (size_t)r * 768, nullptr, XBIG, 768, 3072, 3072);
    }
  }
}

// Round 11
// 470.628 us; speedup vs baseline: 1.0498x; 1.0076x over previous
//
#include <hip/hip_runtime.h>
#include <hip/hip_bf16.h>

using bf16 = __hip_bfloat16;
using bf16x8 = __attribute__((ext_vector_type(8))) __bf16;
using f32x4  = __attribute__((ext_vector_type(4))) float;
using u32x4  = __attribute__((ext_vector_type(4))) unsigned;
typedef unsigned short ushort_t;

#define BM 128
#define BN 128
#define BK 32

// B=4, L=512, D=768, W=12, K_spans=6144, rows_out = B*K = 24576

__device__ __forceinline__ void gl_lds16(const void* g, void* l) {
  __builtin_amdgcn_global_load_lds(
      (const __attribute__((address_space(1))) void*)g,
      (__attribute__((address_space(3))) void*)l, 16, 0, 0);
}

__device__ __forceinline__ ushort_t f2bf(float f) {  // RNE fp32->bf16
  unsigned u = __float_as_uint(f);
  u += 0x7FFF + ((u >> 16) & 1);
  return (ushort_t)(u >> 16);
}

// flags[0]=1 if float inputs are stored as bf16 (else fp32)
// flags[1]=1 if span_idx is int64 (else int32)
__global__ void sniff(const unsigned* __restrict__ w1,
                      const unsigned* __restrict__ idx, int* flags) {
  __shared__ int cnt[2];
  if (threadIdx.x == 0) { cnt[0] = 0; cnt[1] = 0; }
  __syncthreads();
  int t = threadIdx.x;  // 256 threads
  int c0 = 0;
  for (int k = 0; k < 4; ++k) {
    unsigned lo = w1[t * 4 + k] & 0xFFFFu;
    unsigned e = (lo >> 7) & 0xFF;
    if (e <= 122) c0++;
  }
  int c1 = (idx[2 * t + 1] != 0) ? 1 : 0;
  atomicAdd(&cnt[0], c0);
  atomicAdd(&cnt[1], c1);
  __syncthreads();
  if (threadIdx.x == 0) {
    flags[0] = (cnt[0] >= 900) ? 1 : 0;
    flags[1] = (cnt[1] == 0) ? 1 : 0;
  }
}

__global__ void norm_idx(const int* __restrict__ flags, const void* __restrict__ src,
                         int* __restrict__ dst) {
  int i = blockIdx.x * 256 + threadIdx.x;  // grid covers exactly 49152
  int v = flags[1] ? (int)((const long long*)src)[i] : ((const int*)src)[i];
  dst[i] = v;
}

// One kernel converts h + all 6 weights into the contiguous bf16 region at dst.
__global__ void cvt_all(const int* __restrict__ flags,
                        const void* s0, const void* s1, const void* s2,
                        const void* s3, const void* s4, const void* s5,
                        const void* s6, ushort_t* __restrict__ dst) {
  long i = ((long)blockIdx.x * 256 + threadIdx.x) * 4;
  const void* src; long off;
  if      (i <  1572864) { src = s0; off = i; }
  else if (i <  3932160) { src = s1; off = i - 1572864; }
  else if (i <  6291456) { src = s2; off = i - 3932160; }
  else if (i <  8650752) { src = s3; off = i - 6291456; }
  else if (i < 11010048) { src = s4; off = i - 8650752; }
  else if (i < 15728640) { src = s5; off = i - 11010048; }
  else                   { src = s6; off = i - 15728640; }
  if (flags[0]) {
    *(ushort4*)(dst + i) = *((const ushort4*)((const ushort_t*)src + off));
  } else {
    float4 f = ((const float4*)src)[off >> 2];
    ushort4 o;
    o.x = f2bf(f.x); o.y = f2bf(f.y); o.z = f2bf(f.z); o.w = f2bf(f.w);
    *(ushort4*)(dst + i) = o;
  }
}

// biases -> fp32, [bs1|bs2|be1|be2|bo1|bo2|zeros] = 11520 + 3072 floats
__global__ void cvt_bias(const int* __restrict__ flags,
                         const void* b0, const void* b1, const void* b2,
                         const void* b3, const void* b4, const void* b5,
                         float* __restrict__ dst) {
  int i = blockIdx.x * 256 + threadIdx.x;
  if (i >= 14592) return;
  if (i >= 11520) { dst[i] = 0.f; return; }  // zero-bias tail
  const void* src; int off;
  if (i < 3072)       { src = b0; off = i; }
  else if (i < 3840)  { src = b1; off = i - 3072; }
  else if (i < 6912)  { src = b2; off = i - 3840; }
  else if (i < 7680)  { src = b3; off = i - 6912; }
  else if (i < 10752) { src = b4; off = i - 7680; }
  else                { src = b5; off = i - 10752; }
  dst[i] = flags[0] ? __bfloat162float(((const bf16*)src)[off])
                    : ((const float*)src)[off];
}

// C[M,N] = act(A[M,K] @ Bw[N,K(bstride)]^T + bias), A optionally gathered.
// Grid: (m-tiles, n-tiles) — m on blockIdx.x so same-A blocks (diff n) have
// linear ids differing by gridDim.x (mult of 8) -> same XCD -> A L2 reuse.
// Dual-launch: blocks with blockIdx.y >= nsplit use the second operand set.
// LDS k-block XOR swizzle kills the 8-way ds_read_b128 conflict.
template <bool GATHER, bool RELU, bool OUTF32>
__global__ __launch_bounds__(256) void gemm_bt(
    const bf16* __restrict__ A, const bf16* __restrict__ A2,
    const bf16* __restrict__ repS, const bf16* __restrict__ repE,
    const int* __restrict__ sidx, int row_base,
    const bf16* __restrict__ Bw, const bf16* __restrict__ Bw2,
    const float* __restrict__ bias, const float* __restrict__ bias2,
    void* __restrict__ C, void* __restrict__ C2, int nsplit,
    int N, int Kdim, int bstride) {
  __shared__ bf16 lA[BM * BK];
  __shared__ bf16 lB[BN * BK];

  const int tid  = threadIdx.x;
  const int lane = tid & 63;
  const int wave = tid >> 6;
  const int wm = wave >> 1, wn = wave & 1;
  int by = blockIdx.y;
  const bf16* Bw_ = Bw; const float* bias_ = bias; void* C_ = C; const bf16* A_ = A;
  if (by >= nsplit) { by -= nsplit; Bw_ = Bw2; bias_ = bias2; C_ = C2; A_ = A2; }
  const int m0 = blockIdx.x * BM;
  const int n0 = by * BN;

  const int srow = tid >> 2;
  const int scol = 8 * ((tid & 3) ^ ((tid >> 3) & 3));

  const bf16 *a0 = nullptr, *a1 = nullptr;
  const bf16 *pS0 = nullptr, *pE0 = nullptr, *pS1 = nullptr, *pE1 = nullptr;
  if (GATHER) {
    int r0 = row_base + m0 + srow;
    int r1 = r0 + 64;
    int b0 = r0 / 6144, b1 = r1 / 6144;
    int s0 = min(max(sidx[2 * r0], 0), 511);
    int e0 = min(max(sidx[2 * r0 + 1], 0), 511);
    int s1 = min(max(sidx[2 * r1], 0), 511);
    int e1 = min(max(sidx[2 * r1 + 1], 0), 511);
    pS0 = repS + ((size_t)b0 * 512 + s0) * 768 + scol;
    pE0 = repE + ((size_t)b0 * 512 + e0) * 768 + scol;
    pS1 = repS + ((size_t)b1 * 512 + s1) * 768 + scol;
    pE1 = repE + ((size_t)b1 * 512 + e1) * 768 + scol;
  } else {
    a0 = A_ + (size_t)(m0 + srow) * Kdim + scol;
    a1 = a0 + (size_t)64 * Kdim;
  }
  const bf16* b0p = Bw_ + (size_t)(n0 + srow) * bstride + scol;
  const bf16* b1p = b0p + (size_t)64 * bstride;

  f32x4 acc[4][4];
  const f32x4 z = {0.f, 0.f, 0.f, 0.f};
#pragma unroll
  for (int i = 0; i < 4; ++i)
#pragma unroll
    for (int j = 0; j < 4; ++j) acc[i][j] = z;

  const int fr = lane & 15;
  const int fk = 8 * ((lane >> 4) ^ ((lane >> 1) & 3));

  for (int k0 = 0; k0 < Kdim; k0 += BK) {
    const bf16 *sa0, *sa1;
    if (GATHER) {
      if (k0 < 768) { sa0 = pS0 + k0; sa1 = pS1 + k0; }
      else          { sa0 = pE0 + (k0 - 768); sa1 = pE1 + (k0 - 768); }
    } else {
      sa0 = a0 + k0; sa1 = a1 + k0;
    }
    gl_lds16(sa0, lA + tid * 8);
    gl_lds16(sa1, lA + 2048 + tid * 8);
    gl_lds16(b0p + k0, lB + tid * 8);
    gl_lds16(b1p + k0, lB + 2048 + tid * 8);
    __syncthreads();

    bf16x8 af[4], bv[4];
#pragma unroll
    for (int i = 0; i < 4; ++i)
      af[i] = *(const bf16x8*)(const void*)(lA + (wm * 64 + i * 16 + fr) * BK + fk);
#pragma unroll
    for (int j = 0; j < 4; ++j)
      bv[j] = *(const bf16x8*)(const void*)(lB + (wn * 64 + j * 16 + fr) * BK + fk);
#pragma unroll
    for (int i = 0; i < 4; ++i)
#pragma unroll
      for (int j = 0; j < 4; ++j)
        acc[i][j] = __builtin_amdgcn_mfma_f32_16x16x32_bf16(af[i], bv[j], acc[i][j], 0, 0, 0);
    __syncthreads();
  }

  float* Cf = (float*)C_;
  bf16*  Cb = (bf16*)C_;
#pragma unroll
  for (int j = 0; j < 4; ++j) {
    int n = n0 + wn * 64 + j * 16 + fr;
    float bj = bias_[n];
#pragma unroll
    for (int i = 0; i < 4; ++i) {
      int mb = m0 + wm * 64 + i * 16 + (lane >> 4) * 4;
#pragma unroll
      for (int r = 0; r < 4; ++r) {
        float v = acc[i][j][r] + bj;
        if (RELU) v = fmaxf(v, 0.f);
        if (OUTF32) Cf[(size_t)(mb + r) * N + n] = v;
        else        Cb[(size_t)(mb + r) * N + n] = __float2bfloat16(v);
      }
    }
  }
}

// 64x64-tile GEMM for the hid->rep stage (M=2048, N=768/set, K=3072, dual).
// 128x128 gemm_bt gave only 192 blocks = 0.75/CU for this shape; 64x64 ->
// 768 blocks (3/CU), 8 KB LDS: latency hidden by TLP. (round-10: −20 µs)
__global__ __launch_bounds__(256) void gemm_bt64(
    const bf16* __restrict__ A, const bf16* __restrict__ A2,
    const bf16* __restrict__ Bw, const bf16* __restrict__ Bw2,
    const float* __restrict__ bias, const float* __restrict__ bias2,
    bf16* __restrict__ C, bf16* __restrict__ C2, int nsplit,
    int N, int Kdim) {
  __shared__ bf16 lA[64 * BK];   // 4 KB
  __shared__ bf16 lB[64 * BK];   // 4 KB

  const int tid  = threadIdx.x;
  const int lane = tid & 63;
  const int wave = tid >> 6;          // 4 waves: 2m x 2n, wave tile 32x32
  const int wm = wave >> 1, wn = wave & 1;
  int by = blockIdx.y;
  const bf16* Bw_ = Bw; const float* bias_ = bias; bf16* C_ = C; const bf16* A_ = A;
  if (by >= nsplit) { by -= nsplit; Bw_ = Bw2; bias_ = bias2; C_ = C2; A_ = A2; }
  const int m0 = blockIdx.x * 64;
  const int n0 = by * 64;

  const int srow = tid >> 2;                          // [0,64)
  const int scol = 8 * ((tid & 3) ^ ((tid >> 3) & 3));

  const bf16* ap = A_  + (size_t)(m0 + srow) * Kdim + scol;
  const bf16* bp = Bw_ + (size_t)(n0 + srow) * Kdim + scol;

  f32x4 acc[2][2];
  const f32x4 z = {0.f, 0.f, 0.f, 0.f};
#pragma unroll
  for (int i = 0; i < 2; ++i)
#pragma unroll
    for (int j = 0; j < 2; ++j) acc[i][j] = z;

  const int fr = lane & 15;
  const int fk = 8 * ((lane >> 4) ^ ((lane >> 1) & 3));

  for (int k0 = 0; k0 < Kdim; k0 += BK) {
    gl_lds16(ap + k0, lA + tid * 8);
    gl_lds16(bp + k0, lB + tid * 8);
    __syncthreads();

    bf16x8 af[2], bv[2];
#pragma unroll
    for (int i = 0; i < 2; ++i)
      af[i] = *(const bf16x8*)(const void*)(lA + (wm * 32 + i * 16 + fr) * BK + fk);
#pragma unroll
    for (int j = 0; j < 2; ++j)
      bv[j] = *(const bf16x8*)(const void*)(lB + (wn * 32 + j * 16 + fr) * BK + fk);
#pragma unroll
    for (int i = 0; i < 2; ++i)
#pragma unroll
      for (int j = 0; j < 2; ++j)
        acc[i][j] = __builtin_amdgcn_mfma_f32_16x16x32_bf16(af[i], bv[j], acc[i][j], 0, 0, 0);
    __syncthreads();
  }

#pragma unroll
  for (int j = 0; j < 2; ++j) {
    int n = n0 + wn * 32 + j * 16 + fr;
    float bj = bias_[n];
#pragma unroll
    for (int i = 0; i < 2; ++i) {
      int mb = m0 + wm * 32 + i * 16 + (lane >> 4) * 4;
#pragma unroll
      for (int r = 0; r < 4; ++r) {
        float v = fmaxf(acc[i][j][r] + bj, 0.f);
        C_[(size_t)(mb + r) * N + n] = __float2bfloat16(v);
      }
    }
  }
}

// Final GEMM, fused gather-add-relu A-staging.
//   A[r][k] = relu(Ps[tok_s(r)][k] + Pe[tok_e(r)][k]),  out = A @ wo2^T + bo2
// Ps/Pe [2048][3072] bf16. N=768, K=3072.
// v11: 64x64 WAVE TILE — cut LDS bytes per FLOP. v7 and v9/v10 are both
// pinned at 226 µs with identical LDS-traffic-per-FLOP (~136KB / 2.1MFLOP
// per block-step; aggregate 33 TB/s ≈ the practical ds_read_b128+write
// ceiling under barriers). Time never moved with schedule/steps/occupancy
// — it moves with LDS traffic. Fragment reuse is the lever: wave tile
// 32x64 reads 6 b128 per 8 MFMA; 64x64 (acc[4][4]) reads 8 b128 per 16
// MFMA = half the reads per FLOP. BM=128 x BN=256 x BK=32, 512 thr, 8
// waves as 2m x 4n, grid (192,3). LDS 48 KB (A 2x8 + B 2x16); VGPR ~120
// -> 16 waves/CU = 2 blocks. B L2 traffic also halves (192 m-blocks per
// panel vs 384). Same staging/swizzle relation (store key (tid>>3)&3 ==
// reader key (row>>1)&3; linear LDS dests, swizzle global-side — rule #21),
// same depth-1 pipeline, A-loads before stageB (pack waits vmcnt(2)).
__global__ __launch_bounds__(512) void gemm_final_fused(
    const ushort_t* __restrict__ Ps, const ushort_t* __restrict__ Pe,
    const int* __restrict__ sidx,
    const bf16* __restrict__ Bw, const float* __restrict__ bias,
    float* __restrict__ out) {
  __shared__ bf16 lA[2 * 4096];   // 16 KB: two 128x32 A buffers
  __shared__ bf16 lB[2 * 8192];   // 32 KB: two 256x32 B buffers

  const int tid  = threadIdx.x;   // 512 threads
  const int lane = tid & 63;
  const int wave = tid >> 6;      // 8 waves: 2m x 4n, wave tile 64x64
  const int wm = wave >> 2, wn = wave & 3;
  const int m0 = blockIdx.x * 128;
  const int n0 = blockIdx.y * 256;

  const int srow = tid >> 2;                          // [0,128)
  const int scol = 8 * ((tid & 3) ^ ((tid >> 3) & 3));  // swizzle (GLOBAL side)

  // A gather: thread stages 16B of row (m0+srow)
  int r0 = m0 + srow;
  int b0 = r0 / 6144;
  int s0 = min(max(sidx[2 * r0], 0), 511);
  int e0 = min(max(sidx[2 * r0 + 1], 0), 511);
  const ushort_t* pS0 = Ps + ((size_t)b0 * 512 + s0) * 3072 + scol;
  const ushort_t* pE0 = Pe + ((size_t)b0 * 512 + e0) * 3072 + scol;

  // B staging: thread covers rows srow and srow+128
  const bf16* bp0 = Bw + (size_t)(n0 + srow) * 3072 + scol;
  const bf16* bp1 = bp0 + (size_t)128 * 3072;

  f32x4 acc[4][4];
  const f32x4 z = {0.f, 0.f, 0.f, 0.f};
#pragma unroll
  for (int i = 0; i < 4; ++i)
#pragma unroll
    for (int j = 0; j < 4; ++j) acc[i][j] = z;

  const int fr = lane & 15;
  const int fk = 8 * ((lane >> 4) ^ ((lane >> 1) & 3));

  // pack one gathered row chunk pair -> relu'd bf16x8 -> LDS
  auto pack_store = [&](u32x4 xs, u32x4 xe, bf16* dst) {
    u32x4 wv;
#pragma unroll
    for (int q = 0; q < 4; ++q) {
      float lo = fmaxf(__uint_as_float(xs[q] << 16) + __uint_as_float(xe[q] << 16), 0.f);
      float hi = fmaxf(__uint_as_float(xs[q] & 0xFFFF0000u) +
                       __uint_as_float(xe[q] & 0xFFFF0000u), 0.f);
      unsigned w;
      asm("v_cvt_pk_bf16_f32 %0, %1, %2" : "=v"(w) : "v"(lo), "v"(hi));
      wv[q] = w;
    }
    *(u32x4*)(void*)dst = wv;
  };

  // ---- prologue: stage tile 0 into buffer 0 ----
  {
    u32x4 xs = *(const u32x4*)(const void*)pS0;
    u32x4 xe = *(const u32x4*)(const void*)pE0;
    gl_lds16(bp0, lB + tid * 8);
    gl_lds16(bp1, lB + 4096 + tid * 8);
    pack_store(xs, xe, lA + tid * 8);
    __syncthreads();
  }

  for (int it = 0; it < 96; ++it) {
    const int curA = (it & 1) << 12;   // 4096-element A buffers
    const int curB = (it & 1) << 13;   // 8192-element B buffers
    const int nxtA = curA ^ 4096;
    const int nxtB = curB ^ 8192;
    const int k1 = (it + 1) * BK;
    const bool pre = (it + 1) < 96;
    u32x4 xs, xe;
    if (pre) {  // A loads first: pack's wait = vmcnt(2), B stays in flight
      xs = *(const u32x4*)(const void*)(pS0 + k1);
      xe = *(const u32x4*)(const void*)(pE0 + k1);
      gl_lds16(bp0 + k1, lB + nxtB + tid * 8);
      gl_lds16(bp1 + k1, lB + nxtB + 4096 + tid * 8);
    }

    bf16x8 af[4], bv[4];
#pragma unroll
    for (int i = 0; i < 4; ++i)
      af[i] = *(const bf16x8*)(const void*)(
          lA + curA + (wm * 64 + i * 16 + fr) * BK + fk);
#pragma unroll
    for (int j = 0; j < 4; ++j)
      bv[j] = *(const bf16x8*)(const void*)(
          lB + curB + (wn * 64 + j * 16 + fr) * BK + fk);
#pragma unroll
    for (int i = 0; i < 4; ++i)
#pragma unroll
      for (int j = 0; j < 4; ++j)
        acc[i][j] = __builtin_amdgcn_mfma_f32_16x16x32_bf16(af[i], bv[j], acc[i][j], 0, 0, 0);

    if (pre) {  // compiler-counted vmcnt, pack, store
      pack_store(xs, xe, lA + nxtA + tid * 8);
    }
    __syncthreads();
  }

#pragma unroll
  for (int j = 0; j < 4; ++j) {
    int n = n0 + wn * 64 + j * 16 + fr;
    float bj = bias[n];
#pragma unroll
    for (int i = 0; i < 4; ++i) {
      int mb = m0 + wm * 64 + i * 16 + (lane >> 4) * 4;
#pragma unroll
      for (int r = 0; r < 4; ++r)
        out[(size_t)(mb + r) * 768 + n] = acc[i][j][r] + bj;
    }
  }
}

extern "C" void kernel_launch(void* const* d_in, const int* in_sizes, int n_in,
                              void* d_out, int out_size, void* d_ws, size_t ws_size,
                              hipStream_t stream) {
  const void* h    = d_in[0];
  const void* sidx = d_in[1];
  const void *ws1 = d_in[2],  *bs1 = d_in[3];
  const void *ws2 = d_in[4],  *bs2 = d_in[5];
  const void *we1 = d_in[6],  *be1 = d_in[7];
  const void *we2 = d_in[8],  *be2 = d_in[9];
  const void *wo1 = d_in[10], *bo1 = d_in[11];
  const void *wo2 = d_in[12], *bo2 = d_in[13];

  // ---- fixed workspace region ----
  char* p = (char*)d_ws;
  int*      flags = (int*)p;
  int*      idx32 = (int*)(p + 256);
  float*    biasf = (float*)(p + 256 + 196608);            // 14592 f32 (incl zeros)
  ushort_t* hb    = (ushort_t*)(p + 256 + 196608 + 65536);
  ushort_t* w1sb  = hb   + (size_t)1572864;
  ushort_t* w2sb  = w1sb + (size_t)2359296;
  ushort_t* w1eb  = w2sb + (size_t)2359296;
  ushort_t* w2eb  = w1eb + (size_t)2359296;
  ushort_t* wo1b  = w2eb + (size_t)2359296;
  ushort_t* wo2b  = wo1b + (size_t)4718592;
  ushort_t* repS  = wo2b + (size_t)2359296;
  ushort_t* repE  = repS + (size_t)1572864;
  char*     R     = (char*)(repE + (size_t)1572864);  // transient region
  size_t fixed = (size_t)(R - (char*)d_ws);
  if (ws_size < fixed) return;
  size_t Rsz = ws_size - fixed;

  const size_t P_BF = (size_t)2 * 2048 * 3072 * 2;  // Ps+Pe bf16 (== phase-A hid)
  int tier = (Rsz >= P_BF) ? 2 : 3;

  dim3 blk(256);
  const int XBIG = 0x40000000;
  sniff<<<1, blk, 0, stream>>>((const unsigned*)ws1, (const unsigned*)sidx, flags);
  norm_idx<<<192, blk, 0, stream>>>(flags, sidx, idx32);
  cvt_all<<<17664, blk, 0, stream>>>(flags, h, ws1, ws2, we1, we2, wo1, wo2, hb);
  cvt_bias<<<57, blk, 0, stream>>>(flags, bs1, bs2, be1, be2, bo1, bo2, biasf);
  const float *bs1f = biasf, *bs2f = biasf + 3072, *be1f = biasf + 3840,
              *be2f = biasf + 6912, *bo1f = biasf + 7680, *bo2f = biasf + 10752,
              *zerof = biasf + 11520;
  float* outf = (float*)d_out;

  if (tier == 2) {
    // Phase A: token MLPs (start+end merged), hid scratch in R (dead after)
    ushort_t* hidS = (ushort_t*)R;
    ushort_t* hidE = hidS + (size_t)2048 * 3072;
    gemm_bt<false, true, false><<<dim3(16, 48), blk, 0, stream>>>(
        (const bf16*)hb, (const bf16*)hb, nullptr, nullptr, nullptr, 0,
        (const bf16*)w1sb, (const bf16*)w1eb, bs1f, be1f,
        hidS, hidE, 24, 3072, 768, 768);
    gemm_bt64<<<dim3(32, 24), blk, 0, stream>>>(
        (const bf16*)hidS, (const bf16*)hidE,
        (const bf16*)w2sb, (const bf16*)w2eb, bs2f, be2f,
        (bf16*)repS, (bf16*)repE, 12, 768, 3072);
    // Phase B': P_s = repS@wo1[:, :768]^T + bo1 ; P_e = repE@wo1[:, 768:]^T
    ushort_t* Ps = (ushort_t*)R;
    ushort_t* Pe = Ps + (size_t)2048 * 3072;
    gemm_bt<false, false, false><<<dim3(16, 48), blk, 0, stream>>>(
        (const bf16*)repS, (const bf16*)repE, nullptr, nullptr, nullptr, 0,
        (const bf16*)wo1b, (const bf16*)wo1b + 768, bo1f, zerof,
        Ps, Pe, 24, 3072, 768, 1536);
    gemm_final_fused<<<dim3(192, 3), dim3(512), 0, stream>>>(
        Ps, Pe, idx32, (const bf16*)wo2b, bo2f, outf);
  } else {
    // Tier 3 fallback: two-pass path, chunked in R
    long long cT = (long long)(Rsz / ((size_t)2 * 3072 * 2));
    cT = (cT / 128) * 128; if (cT > 2048) cT = 2048;
    long long cO = (long long)(Rsz / ((size_t)3072 * 2));
    cO = (cO / 128) * 128; if (cO > 24576) cO = 24576;
    if (cT < 128 || cO < 128) return;
    ushort_t* scr = (ushort_t*)R;
    for (long long r = 0; r < 2048; r += cT) {
      long long mc = 2048 - r < cT ? 2048 - r : cT;
      ushort_t* hidS = scr;
      ushort_t* hidE = scr + (size_t)cT * 3072;
      gemm_bt<false, true, false><<<dim3(mc / 128, 48), blk, 0, stream>>>(
          (const bf16*)hb + r * 768, (const bf16*)hb + r * 768,
          nullptr, nullptr, nullptr, 0,
          (const bf16*)w1sb, (const bf16*)w1eb, bs1f, be1f,
          hidS, hidE, 24, 3072, 768, 768);
      gemm_bt<false, true, false><<<dim3(mc / 128, 12), blk, 0, stream>>>(
          (const bf16*)hidS, (const bf16*)hidE, nullptr, nullptr, nullptr, 0,
          (const bf16*)w2sb, (const bf16*)w2eb, bs2f, be2f,
          (bf16*)repS + r * 768, (bf16*)repE + r * 768, 6, 768, 3072, 3072);
    }
    for (long long r = 0; r < 24576; r += cO) {
      long long mc = 24576 - r < cO ? 24576 - r : cO;
      gemm_bt<true, true, false><<<dim3(mc / 128, 24), blk, 0, stream>>>(
          nullptr, nullptr, (const bf16*)repS, (const bf16*)repE, idx32, (int)r,
          (const bf16*)wo1b, nullptr, bo1f, nullptr,
          scr, nullptr, XBIG, 3072, 1536, 1536);
      gemm_bt<false, false, true><<<dim3(mc / 128, 6), blk, 0, stream>>>(
          (const bf16*)scr, nullptr, nullptr, nullptr, nullptr, 0,
          (const bf16*)wo2b, nullptr, bo2f, nullptr,
          outf + (size_t)r * 768, nullptr, XBIG, 768, 3072, 3072);
    }
  }
}